// Round 1
// baseline (1608.059 us; speedup 1.0000x reference)
//
#include <hip/hip_runtime.h>
#include <math.h>

#define BB 2
#define NN 128
#define DD 128     // DIM
#define HH 8
#define DHH 32
#define DI 256     // H*DH
#define DM 512
#define SS 5
#define SDI 1280   // S*DI
#define HS 40      // H*S
#define M1 3
#define M2 5

__device__ __forceinline__ float fast_sigmoid(float x){ return 1.0f/(1.0f+__expf(-x)); }

// ---------------------------------------------------------------------------
// Kernel A: per-node precompute. grid = B*N blocks x 256 threads.
// LN(h) -> hi,hj ; q=hi@Wq ; k=hj@Wk ; v=silu(hj@Wv1+b)@Wv2+b ; pv likewise;
// gates=sigmoid(hi@Wg+bg)
// ---------------------------------------------------------------------------
__global__ __launch_bounds__(256) void node_pre(
    const float* __restrict__ h,
    const float* __restrict__ g_hi, const float* __restrict__ g_hj,
    const float* __restrict__ Wq, const float* __restrict__ Wk,
    const float* __restrict__ Wv1, const float* __restrict__ bv1,
    const float* __restrict__ Wv2, const float* __restrict__ bv2,
    const float* __restrict__ Wpv1, const float* __restrict__ bpv1,
    const float* __restrict__ Wpv2, const float* __restrict__ bpv2,
    const float* __restrict__ Wg, const float* __restrict__ bg,
    float* __restrict__ q_ws, float* __restrict__ k_ws,
    float* __restrict__ v_ws, float* __restrict__ pv_ws, float* __restrict__ g_ws)
{
    const int node = blockIdx.x;       // b*N + n
    const int tid  = threadIdx.x;
    __shared__ float s_hi[DD], s_hj[DD], s_a[DM], s_b[DM];
    __shared__ float s_red[4];

    float hval = (tid < DD) ? h[node*DD + tid] : 0.0f;
    float s1 = hval, s2 = hval*hval;
    #pragma unroll
    for (int off=32; off; off>>=1){
        s1 += __shfl_xor(s1, off);
        s2 += __shfl_xor(s2, off);
    }
    if (tid < DD && (tid & 63) == 0){
        s_red[(tid>>6)*2+0] = s1;
        s_red[(tid>>6)*2+1] = s2;
    }
    __syncthreads();
    const float mu   = (s_red[0] + s_red[2]) * (1.0f/DD);
    const float var  = (s_red[1] + s_red[3]) * (1.0f/DD) - mu*mu;
    const float rstd = rsqrtf(var + 1e-5f);
    if (tid < DD){
        float c = (hval - mu) * rstd;
        s_hi[tid] = c * g_hi[tid];
        s_hj[tid] = c * g_hj[tid];
    }
    __syncthreads();

    // q, k : one output column per thread (coalesced weight reads)
    {
        float aq = 0.f, ak = 0.f;
        for (int d=0; d<DD; ++d){
            aq = fmaf(s_hi[d], Wq[d*DI + tid], aq);
            ak = fmaf(s_hj[d], Wk[d*DI + tid], ak);
        }
        q_ws[node*DI + tid] = aq;
        k_ws[node*DI + tid] = ak;
    }
    // hidden silu layers for v / pv
    #pragma unroll
    for (int p=0; p<2; ++p){
        int oo = tid + p*256;
        float a1 = bv1[oo], a2 = bpv1[oo];
        for (int d=0; d<DD; ++d){
            float x = s_hj[d];
            a1 = fmaf(x, Wv1 [d*DM + oo], a1);
            a2 = fmaf(x, Wpv1[d*DM + oo], a2);
        }
        s_a[oo] = a1 * fast_sigmoid(a1);
        s_b[oo] = a2 * fast_sigmoid(a2);
    }
    __syncthreads();
    // v / pv (S*DI = 1280 outputs each)
    #pragma unroll
    for (int p=0; p<SS; ++p){
        int oo = tid + p*256;
        float a1 = bv2[oo], a2 = bpv2[oo];
        for (int c=0; c<DM; ++c){
            a1 = fmaf(s_a[c], Wv2 [c*SDI + oo], a1);
            a2 = fmaf(s_b[c], Wpv2[c*SDI + oo], a2);
        }
        v_ws [node*SDI + oo] = a1;
        pv_ws[node*SDI + oo] = a2;
    }
    // gates
    if (tid < HS){
        float a = bg[tid];
        for (int d=0; d<DD; ++d) a = fmaf(s_hi[d], Wg[d*HS + tid], a);
        g_ws[node*HS + tid] = fast_sigmoid(a);
    }
}

// ---------------------------------------------------------------------------
// Kernel B1: per (b,i) block: sim[j,h,s] = sum_dh q*k*silu(t@Wek), softmax_j.
// grid = B*N blocks x 512 threads (2 j-groups x 256 output-threads).
// ---------------------------------------------------------------------------
__global__ __launch_bounds__(512) void sim_kernel(
    const float* __restrict__ t_ij,
    const float* __restrict__ Wek,
    const float* __restrict__ q_ws, const float* __restrict__ k_ws,
    float* __restrict__ attn_ws)
{
    const int node = blockIdx.x;       // b*N + i
    const int b    = node >> 7;
    const int tid  = threadIdx.x;
    const int o    = tid & 255;
    const int grp  = tid >> 8;

    __shared__ float s_sim[NN*HS];     // 20 KB
    __shared__ float s_t[16*DD];       // 8 KB
    __shared__ float s_q[DI];

    if (tid < DI) s_q[tid] = q_ws[node*DI + tid];

    for (int jo=0; jo<8; ++jo){        // 16 j's per iteration
        __syncthreads();
        #pragma unroll
        for (int it=0; it<4; ++it){
            int idx = tid + it*512;    // rows contiguous
            s_t[idx] = t_ij[(node*NN + jo*16)*DD + idx];
        }
        __syncthreads();

        float acc[SS][8];
        #pragma unroll
        for (int s=0; s<SS; ++s)
            #pragma unroll
            for (int jj=0; jj<8; ++jj) acc[s][jj] = 0.f;

        const float* wp = Wek + o;
        for (int d=0; d<DD; ++d){
            float w0 = wp[d*SDI + 0*DI];
            float w1 = wp[d*SDI + 1*DI];
            float w2 = wp[d*SDI + 2*DI];
            float w3 = wp[d*SDI + 3*DI];
            float w4 = wp[d*SDI + 4*DI];
            #pragma unroll
            for (int jj=0; jj<8; ++jj){
                float tv = s_t[(grp*8+jj)*DD + d];
                acc[0][jj] = fmaf(tv, w0, acc[0][jj]);
                acc[1][jj] = fmaf(tv, w1, acc[1][jj]);
                acc[2][jj] = fmaf(tv, w2, acc[2][jj]);
                acc[3][jj] = fmaf(tv, w3, acc[3][jj]);
                acc[4][jj] = fmaf(tv, w4, acc[4][jj]);
            }
        }
        const int   hh = o >> 5;       // head
        const float qv = s_q[o];
        #pragma unroll
        for (int jj=0; jj<8; ++jj){
            int j = jo*16 + grp*8 + jj;
            float qk = qv * k_ws[(b*NN + j)*DI + o];
            #pragma unroll
            for (int s=0; s<SS; ++s){
                float e  = acc[s][jj];
                float se = e * (1.0f/(1.0f+__expf(-e)));   // silu
                float part = qk * se;
                #pragma unroll
                for (int off=16; off; off>>=1) part += __shfl_xor(part, off);
                if ((tid & 31) == 0) s_sim[j*HS + hh*SS + s] = part;  // reduced over dh
            }
        }
    }
    __syncthreads();

    // softmax over j for each (h,s): wave w == head h handles its 5 s-slots
    {
        const int w = tid >> 6;
        const int l = tid & 63;
        #pragma unroll
        for (int pp=0; pp<SS; ++pp){
            int p = w*SS + pp;
            float v0 = s_sim[l*HS + p];
            float v1 = s_sim[(l+64)*HS + p];
            float m = fmaxf(v0, v1);
            #pragma unroll
            for (int off=32; off; off>>=1) m = fmaxf(m, __shfl_xor(m, off));
            float e0 = __expf(v0 - m), e1 = __expf(v1 - m);
            float ss = e0 + e1;
            #pragma unroll
            for (int off=32; off; off>>=1) ss += __shfl_xor(ss, off);
            float inv = 1.0f/ss;
            attn_ws[node*(NN*HS) + l*HS + p]      = e0*inv;
            attn_ws[node*(NN*HS) + (l+64)*HS + p] = e1*inv;
        }
    }
}

// ---------------------------------------------------------------------------
// Kernel B2: per (b,i) block: ev = t@Wev ; g_sea = (attn*v + ev*pv)*gate ;
// out[j,s,:] = g_sea[s,:]@Wo ; accumulate h_out / x1_out / x2_out over j.
// grid = B*N blocks x 512 threads.
// ---------------------------------------------------------------------------
__global__ __launch_bounds__(512) void out_kernel(
    const float* __restrict__ h, const float* __restrict__ t_ij,
    const float* __restrict__ r1, const float* __restrict__ r2,
    const float* __restrict__ x1, const float* __restrict__ x2,
    const float* __restrict__ Wev, const float* __restrict__ Wo,
    const float* __restrict__ v_ws, const float* __restrict__ pv_ws,
    const float* __restrict__ g_ws, const float* __restrict__ attn_ws,
    float* __restrict__ out_h, float* __restrict__ out_x1, float* __restrict__ out_x2)
{
    const int node = blockIdx.x;       // b*N + i
    const int b    = node >> 7;
    const int tid  = threadIdx.x;
    const int o    = tid & 255;
    const int grp  = tid >> 8;
    const int d_   = tid & 127;
    const int sg   = tid >> 7;         // 0..3, wave-uniform

    __shared__ float s_ev[8*SDI];      // 40 KB: raw ev, then g_sea in place
    __shared__ float s_t[8*DD];        // 4 KB
    __shared__ float s_at[8*HS];       // attn slice for this chunk
    __shared__ float s_g[HS];
    __shared__ float s_cmb[DD*(M1+M2)];

    if (tid < HS) s_g[tid] = g_ws[node*HS + tid];

    float acc_h = 0.f;
    float acc_x1[M1] = {0.f,0.f,0.f};          // sg3
    float acc_r1[M1] = {0.f,0.f,0.f};          // sg1
    float acc_x2[M2] = {0.f,0.f,0.f,0.f,0.f};  // sg0
    float acc_r2[M2] = {0.f,0.f,0.f,0.f,0.f};  // sg2

    for (int jo=0; jo<16; ++jo){       // 8 j's per iteration
        __syncthreads();
        #pragma unroll
        for (int it=0; it<2; ++it){
            int idx = tid + it*512;
            s_t[idx] = t_ij[(node*NN + jo*8)*DD + idx];
        }
        if (tid < 8*HS) s_at[tid] = attn_ws[node*(NN*HS) + jo*8*HS + tid];
        __syncthreads();

        // ev matvec: 2 groups x 4 j's
        {
            float acc[SS][4];
            #pragma unroll
            for (int s=0; s<SS; ++s)
                #pragma unroll
                for (int jj=0; jj<4; ++jj) acc[s][jj] = 0.f;
            const float* wp = Wev + o;
            for (int d=0; d<DD; ++d){
                float w0 = wp[d*SDI + 0*DI];
                float w1 = wp[d*SDI + 1*DI];
                float w2 = wp[d*SDI + 2*DI];
                float w3 = wp[d*SDI + 3*DI];
                float w4 = wp[d*SDI + 4*DI];
                #pragma unroll
                for (int jj=0; jj<4; ++jj){
                    float tv = s_t[(grp*4+jj)*DD + d];
                    acc[0][jj] = fmaf(tv, w0, acc[0][jj]);
                    acc[1][jj] = fmaf(tv, w1, acc[1][jj]);
                    acc[2][jj] = fmaf(tv, w2, acc[2][jj]);
                    acc[3][jj] = fmaf(tv, w3, acc[3][jj]);
                    acc[4][jj] = fmaf(tv, w4, acc[4][jj]);
                }
            }
            #pragma unroll
            for (int jj=0; jj<4; ++jj)
                #pragma unroll
                for (int s=0; s<SS; ++s)
                    s_ev[(grp*4+jj)*SDI + s*DI + o] = acc[s][jj];
        }
        __syncthreads();

        for (int jj8=0; jj8<8; ++jj8){
            int j = jo*8 + jj8;
            // g_sea build, in place over s_ev[jj8]
            {
                int hh = o >> 5;
                int base = (b*NN + j)*SDI;
                if (grp == 0){
                    #pragma unroll
                    for (int s=0; s<SS; s+=2){       // s = 0,2,4
                        float at = s_at[jj8*HS + hh*SS + s];
                        float vv = v_ws [base + s*DI + o];
                        float pp = pv_ws[base + s*DI + o];
                        float ee = s_ev[jj8*SDI + s*DI + o];
                        s_ev[jj8*SDI + s*DI + o] = (at*vv + ee*pp) * s_g[hh*SS + s];
                    }
                } else {
                    #pragma unroll
                    for (int s=1; s<SS; s+=2){       // s = 1,3
                        float at = s_at[jj8*HS + hh*SS + s];
                        float vv = v_ws [base + s*DI + o];
                        float pp = pv_ws[base + s*DI + o];
                        float ee = s_ev[jj8*SDI + s*DI + o];
                        s_ev[jj8*SDI + s*DI + o] = (at*vv + ee*pp) * s_g[hh*SS + s];
                    }
                }
            }
            __syncthreads();
            // Wo contraction + per-s output accumulation (branches wave-uniform)
            if (sg == 0){
                float o0 = 0.f, o4 = 0.f;
                #pragma unroll 4
                for (int c=0; c<DI; ++c){
                    float wo = Wo[c*DD + d_];
                    o0 = fmaf(s_ev[jj8*SDI + 0*DI + c], wo, o0);
                    o4 = fmaf(s_ev[jj8*SDI + 4*DI + c], wo, o4);
                }
                acc_h += o0;
                int xb = ((b*NN + j)*DD + d_)*M2;
                #pragma unroll
                for (int m=0; m<M2; ++m) acc_x2[m] = fmaf(x2[xb+m], o4, acc_x2[m]);
            } else if (sg == 1){
                float o1 = 0.f;
                #pragma unroll 4
                for (int c=0; c<DI; ++c)
                    o1 = fmaf(s_ev[jj8*SDI + 1*DI + c], Wo[c*DD + d_], o1);
                int rb = (node*NN + j)*M1;
                #pragma unroll
                for (int m=0; m<M1; ++m) acc_r1[m] = fmaf(r1[rb+m], o1, acc_r1[m]);
            } else if (sg == 2){
                float o2 = 0.f;
                #pragma unroll 4
                for (int c=0; c<DI; ++c)
                    o2 = fmaf(s_ev[jj8*SDI + 2*DI + c], Wo[c*DD + d_], o2);
                int rb = (node*NN + j)*M2;
                #pragma unroll
                for (int m=0; m<M2; ++m) acc_r2[m] = fmaf(r2[rb+m], o2, acc_r2[m]);
            } else {
                float o3 = 0.f;
                #pragma unroll 4
                for (int c=0; c<DI; ++c)
                    o3 = fmaf(s_ev[jj8*SDI + 3*DI + c], Wo[c*DD + d_], o3);
                int xb = ((b*NN + j)*DD + d_)*M1;
                #pragma unroll
                for (int m=0; m<M1; ++m) acc_x1[m] = fmaf(x1[xb+m], o3, acc_x1[m]);
            }
            // no barrier needed here: next jj8 writes a disjoint s_ev region
        }
    }

    // combine partial accumulators across thread groups and write outputs
    __syncthreads();
    if (sg == 3){
        #pragma unroll
        for (int m=0; m<M1; ++m) s_cmb[d_*M1 + m] = acc_x1[m];
    } else if (sg == 0){
        #pragma unroll
        for (int m=0; m<M2; ++m) s_cmb[DD*M1 + d_*M2 + m] = acc_x2[m];
    }
    __syncthreads();
    if (sg == 0){
        out_h[node*DD + d_] = h[node*DD + d_] + acc_h;
    } else if (sg == 1){
        #pragma unroll
        for (int m=0; m<M1; ++m)
            out_x1[(node*DD + d_)*M1 + m] = s_cmb[d_*M1 + m] + acc_r1[m];
    } else if (sg == 2){
        #pragma unroll
        for (int m=0; m<M2; ++m)
            out_x2[(node*DD + d_)*M2 + m] = s_cmb[DD*M1 + d_*M2 + m] + acc_r2[m];
    }
}

// ---------------------------------------------------------------------------
extern "C" void kernel_launch(void* const* d_in, const int* in_sizes, int n_in,
                              void* d_out, int out_size, void* d_ws, size_t ws_size,
                              hipStream_t stream)
{
    (void)in_sizes; (void)n_in; (void)out_size; (void)ws_size;
    const float* h    = (const float*)d_in[0];
    const float* t_ij = (const float*)d_in[1];
    const float* r1   = (const float*)d_in[2];
    const float* r2   = (const float*)d_in[3];
    const float* x1   = (const float*)d_in[4];
    const float* x2   = (const float*)d_in[5];
    const float* g_hi = (const float*)d_in[6];
    const float* g_hj = (const float*)d_in[7];
    const float* Wq   = (const float*)d_in[8];
    const float* Wk   = (const float*)d_in[9];
    const float* Wv1  = (const float*)d_in[10];
    const float* bv1  = (const float*)d_in[11];
    const float* Wv2  = (const float*)d_in[12];
    const float* bv2  = (const float*)d_in[13];
    const float* Wpv1 = (const float*)d_in[14];
    const float* bpv1 = (const float*)d_in[15];
    const float* Wpv2 = (const float*)d_in[16];
    const float* bpv2 = (const float*)d_in[17];
    const float* Wek  = (const float*)d_in[18];
    const float* Wev  = (const float*)d_in[19];
    const float* Wg   = (const float*)d_in[20];
    const float* bg   = (const float*)d_in[21];
    const float* Wo   = (const float*)d_in[22];

    float* ws      = (float*)d_ws;
    float* q_ws    = ws;                         // 65536
    float* k_ws    = q_ws    + BB*NN*DI;         // 65536
    float* v_ws    = k_ws    + BB*NN*DI;         // 327680
    float* pv_ws   = v_ws    + BB*NN*SDI;        // 327680
    float* g_ws    = pv_ws   + BB*NN*SDI;        // 10240
    float* attn_ws = g_ws    + BB*NN*HS;         // 1310720

    float* out_h  = (float*)d_out;
    float* out_x1 = out_h  + BB*NN*DD;
    float* out_x2 = out_x1 + BB*NN*DD*M1;

    node_pre<<<BB*NN, 256, 0, stream>>>(h, g_hi, g_hj, Wq, Wk, Wv1, bv1, Wv2, bv2,
        Wpv1, bpv1, Wpv2, bpv2, Wg, bg, q_ws, k_ws, v_ws, pv_ws, g_ws);

    sim_kernel<<<BB*NN, 512, 0, stream>>>(t_ij, Wek, q_ws, k_ws, attn_ws);

    out_kernel<<<BB*NN, 512, 0, stream>>>(h, t_ij, r1, r2, x1, x2, Wev, Wo,
        v_ws, pv_ws, g_ws, attn_ws, out_h, out_x1, out_x2);
}

// Round 2
// 279.792 us; speedup vs baseline: 5.7473x; 5.7473x over previous
//
#include <hip/hip_runtime.h>
#include <math.h>

#define BB 2
#define NN 128
#define DD 128     // DIM
#define HH 8
#define DI 256     // H*DH
#define DM 512
#define SS 5
#define SDI 1280   // S*DI
#define HS 40      // H*S
#define M1 3
#define M2 5

typedef __attribute__((ext_vector_type(8))) short bf16x8_t;
typedef __attribute__((ext_vector_type(4))) float f32x4_t;

__device__ __forceinline__ float fast_sigmoid(float x){ return __fdividef(1.0f, 1.0f+__expf(-x)); }
__device__ __forceinline__ unsigned short f2bf(float f){
    union { float f; unsigned u; } v; v.f = f;
    unsigned r = v.u + 0x7FFFu + ((v.u>>16)&1u);   // RNE
    return (unsigned short)(r>>16);
}
__device__ __forceinline__ unsigned pk2(float a, float b){
    return (unsigned)f2bf(a) | ((unsigned)f2bf(b)<<16);
}

// ---------------------------------------------------------------------------
// pack_weights: bf16-transpose Wek,Wev -> [1280][128]; Wo -> WoT[128][256];
// Wv2+Wpv2 -> W2T[2560][512]
// ---------------------------------------------------------------------------
__global__ __launch_bounds__(256) void pack_weights(
    const float* __restrict__ Wek, const float* __restrict__ Wev,
    const float* __restrict__ Wo,  const float* __restrict__ Wv2,
    const float* __restrict__ Wpv2,
    unsigned short* __restrict__ WekT, unsigned short* __restrict__ WevT,
    unsigned short* __restrict__ WoT, unsigned short* __restrict__ W2T)
{
    const int stride = gridDim.x * blockDim.x;
    const int idx0 = blockIdx.x*blockDim.x + threadIdx.x;
    for (int i = idx0; i < DD*SDI; i += stride){
        int d = i / SDI, o = i % SDI;
        WekT[o*DD + d] = f2bf(Wek[i]);
        WevT[o*DD + d] = f2bf(Wev[i]);
    }
    for (int i = idx0; i < DI*DD; i += stride){
        int c = i / DD, d = i % DD;
        WoT[d*DI + c] = f2bf(Wo[i]);
    }
    for (int i = idx0; i < DM*SDI; i += stride){
        int c = i / SDI, o = i % SDI;
        W2T[o*DM + c]         = f2bf(Wv2[i]);
        W2T[(SDI + o)*DM + c] = f2bf(Wpv2[i]);
    }
}

// ---------------------------------------------------------------------------
// node_pre: LN -> q,k,gates + silu hidden (bf16) for the v2/pv2 GEMM
// ---------------------------------------------------------------------------
__global__ __launch_bounds__(256) void node_pre(
    const float* __restrict__ h,
    const float* __restrict__ g_hi, const float* __restrict__ g_hj,
    const float* __restrict__ Wq, const float* __restrict__ Wk,
    const float* __restrict__ Wv1, const float* __restrict__ bv1,
    const float* __restrict__ Wpv1, const float* __restrict__ bpv1,
    const float* __restrict__ Wg, const float* __restrict__ bg,
    float* __restrict__ q_ws, float* __restrict__ k_ws,
    unsigned short* __restrict__ hid_ws, float* __restrict__ g_ws)
{
    const int node = blockIdx.x;
    const int tid  = threadIdx.x;
    __shared__ float s_hi[DD], s_hj[DD];
    __shared__ float s_red[4];

    float hval = (tid < DD) ? h[node*DD + tid] : 0.0f;
    float s1 = hval, s2 = hval*hval;
    #pragma unroll
    for (int off=32; off; off>>=1){
        s1 += __shfl_xor(s1, off);
        s2 += __shfl_xor(s2, off);
    }
    if (tid < DD && (tid & 63) == 0){
        s_red[(tid>>6)*2+0] = s1;
        s_red[(tid>>6)*2+1] = s2;
    }
    __syncthreads();
    const float mu   = (s_red[0] + s_red[2]) * (1.0f/DD);
    const float var  = (s_red[1] + s_red[3]) * (1.0f/DD) - mu*mu;
    const float rstd = rsqrtf(var + 1e-5f);
    if (tid < DD){
        float c = (hval - mu) * rstd;
        s_hi[tid] = c * g_hi[tid];
        s_hj[tid] = c * g_hj[tid];
    }
    __syncthreads();

    {
        float aq = 0.f, ak = 0.f;
        for (int d=0; d<DD; ++d){
            aq = fmaf(s_hi[d], Wq[d*DI + tid], aq);
            ak = fmaf(s_hj[d], Wk[d*DI + tid], ak);
        }
        q_ws[node*DI + tid] = aq;
        k_ws[node*DI + tid] = ak;
    }
    #pragma unroll
    for (int p=0; p<2; ++p){
        int oo = tid + p*256;
        float a1 = bv1[oo], a2 = bpv1[oo];
        for (int d=0; d<DD; ++d){
            float x = s_hj[d];
            a1 = fmaf(x, Wv1 [d*DM + oo], a1);
            a2 = fmaf(x, Wpv1[d*DM + oo], a2);
        }
        hid_ws[node*1024 + oo]       = f2bf(a1 * fast_sigmoid(a1));
        hid_ws[node*1024 + 512 + oo] = f2bf(a2 * fast_sigmoid(a2));
    }
    if (tid < HS){
        float a = bg[tid];
        for (int d=0; d<DD; ++d) a = fmaf(s_hi[d], Wg[d*HS + tid], a);
        g_ws[node*HS + tid] = fast_sigmoid(a);
    }
}

// ---------------------------------------------------------------------------
// v2_gemm: [256 nodes x 2560] = hid[256 x (512|512)] @ (Wv2|Wpv2), MFMA.
// grid 640 = 160 n-tiles x 4 m-quarters; 256 thr = 4 waves (1 m-tile each).
// ---------------------------------------------------------------------------
__global__ __launch_bounds__(256) void v2_gemm(
    const unsigned short* __restrict__ hid_ws,
    const unsigned short* __restrict__ W2T,
    const float* __restrict__ bv2, const float* __restrict__ bpv2,
    float* __restrict__ v_ws, float* __restrict__ pv_ws)
{
    const int blk = blockIdx.x;
    const int nt = blk % 160, mq = blk / 160;
    const int tid = threadIdx.x, lane = tid & 63, w = tid >> 6;
    const int l15 = lane & 15, g4 = lane >> 4;
    const int o = nt*16 + l15;
    const int m0 = mq*64 + w*16;
    const int koff = (o < SDI) ? 0 : DM;
    const unsigned short* hrow = hid_ws + (m0 + l15)*1024 + koff + 8*g4;
    const unsigned short* wrow = W2T + o*DM + 8*g4;
    f32x4_t c = {0.f,0.f,0.f,0.f};
    #pragma unroll
    for (int ks=0; ks<16; ++ks){
        bf16x8_t a  = *(const bf16x8_t*)(hrow + 32*ks);
        bf16x8_t bq = *(const bf16x8_t*)(wrow + 32*ks);
        c = __builtin_amdgcn_mfma_f32_16x16x32_bf16(a, bq, c, 0, 0, 0);
    }
    const int oc = (o < SDI) ? o : (o - SDI);
    const float bb = (o < SDI) ? bv2[oc] : bpv2[oc];
    float* dst = (o < SDI) ? v_ws : pv_ws;
    #pragma unroll
    for (int r=0; r<4; ++r){
        int nd = m0 + 4*g4 + r;
        dst[nd*SDI + oc] = c[r] + bb;
    }
}

// ---------------------------------------------------------------------------
// edge_kernel: fused sim/softmax/ev/gsea/Wo/reductions per (b,i).
// ---------------------------------------------------------------------------
#define SM_SIM 65536       // f32 [128][40]  (region 0..65536 = s_T then s_P)
#define SM_Q   86016
#define SM_G   87040
#define SM_R1  87296
#define SM_R2  88832
#define SM_TOTAL 91392

__global__ __launch_bounds__(512) void edge_kernel(
    const float* __restrict__ h, const float* __restrict__ t_ij,
    const float* __restrict__ r1, const float* __restrict__ r2,
    const float* __restrict__ x1, const float* __restrict__ x2,
    const unsigned short* __restrict__ WekT, const unsigned short* __restrict__ WevT,
    const unsigned short* __restrict__ WoT,
    const float* __restrict__ q_ws, const float* __restrict__ k_ws,
    const float* __restrict__ v_ws, const float* __restrict__ pv_ws,
    const float* __restrict__ g_ws,
    float* __restrict__ out_h, float* __restrict__ out_x1, float* __restrict__ out_x2)
{
    extern __shared__ char sm[];
    float* sSIM = (float*)(sm + SM_SIM);
    float* sQ   = (float*)(sm + SM_Q);
    float* sG   = (float*)(sm + SM_G);
    float* sR1  = (float*)(sm + SM_R1);
    float* sR2  = (float*)(sm + SM_R2);

    const int node = blockIdx.x;
    const int b    = node >> 7;
    const int tid  = threadIdx.x;
    const int lane = tid & 63;
    const int w    = tid >> 6;
    const int l15  = lane & 15;
    const int g4   = lane >> 4;

    if (tid < DI) sQ[tid] = q_ws[node*DI + tid];
    if (tid >= DI && tid < DI+HS) sG[tid-DI] = g_ws[node*HS + (tid-DI)];
    if (tid < NN*M1) sR1[tid] = r1[node*NN*M1 + tid];
    sR2[tid] = r2[node*NN*M2 + tid];
    if (tid < NN*M2 - 512) sR2[512+tid] = r2[node*NN*M2 + 512 + tid];

    // stage T -> bf16 LDS, XOR-swizzled rows
    {
        const int j = tid >> 2, q4 = tid & 3;
        const float* src = t_ij + (size_t)(node*NN + j)*DD + q4*32;
        #pragma unroll
        for (int u=0; u<8; ++u){
            float4 tv = *(const float4*)(src + u*4);
            int d0 = q4*32 + u*4;
            int addr = j*256 + ((2*d0) ^ ((j&7)<<4));
            uint2 pkk; pkk.x = pk2(tv.x, tv.y); pkk.y = pk2(tv.z, tv.w);
            *(uint2*)(sm + addr) = pkk;
        }
    }
    __syncthreads();

    // persistent B-fragments of T^T for this wave's 16 j-columns
    const int jcol = 16*w + l15;
    bf16x8_t bT[4];
    #pragma unroll
    for (int ks=0; ks<4; ++ks){
        int addr = jcol*256 + ((2*(32*ks + 8*g4)) ^ ((jcol&7)<<4));
        bT[ks] = *(const bf16x8_t*)(sm + addr);
    }

    // ---------------- phase 1: sim[j,h,s] ----------------
    const float* kjrow = k_ws + (size_t)(b*NN + jcol)*DI;
    for (int mt=0; mt<80; mt+=2){
        float pair = 0.f;
        #pragma unroll
        for (int t2=0; t2<2; ++t2){
            int mtt = mt + t2;
            const unsigned short* ap = WekT + (size_t)(mtt*16 + l15)*DD + 8*g4;
            f32x4_t c = {0.f,0.f,0.f,0.f};
            #pragma unroll
            for (int ks=0; ks<4; ++ks){
                bf16x8_t a = *(const bf16x8_t*)(ap + 32*ks);
                c = __builtin_amdgcn_mfma_f32_16x16x32_bf16(a, bT[ks], c, 0, 0, 0);
            }
            int o0 = mtt*16 + 4*g4;
            int rem0 = o0 & 255;
            float4 qv = *(const float4*)(sQ + rem0);
            float4 kv = *(const float4*)(kjrow + rem0);
            float part;
            part  = (c[0]*fast_sigmoid(c[0])) * qv.x * kv.x;
            part += (c[1]*fast_sigmoid(c[1])) * qv.y * kv.y;
            part += (c[2]*fast_sigmoid(c[2])) * qv.z * kv.z;
            part += (c[3]*fast_sigmoid(c[3])) * qv.w * kv.w;
            part += __shfl_xor(part, 16);
            part += __shfl_xor(part, 32);
            pair += part;
        }
        if (g4 == 0){
            int s = mt >> 4, hh = (mt >> 1) & 7;
            sSIM[jcol*HS + hh*SS + s] = pair;
        }
    }
    __syncthreads();

    // ---------------- phase 2: softmax over j ----------------
    #pragma unroll
    for (int pp=0; pp<SS; ++pp){
        int p = w*SS + pp;
        float v0 = sSIM[lane*HS + p];
        float v1 = sSIM[(lane+64)*HS + p];
        float m = fmaxf(v0, v1);
        #pragma unroll
        for (int off=32; off; off>>=1) m = fmaxf(m, __shfl_xor(m, off));
        float e0 = __expf(v0 - m), e1 = __expf(v1 - m);
        float ssum = e0 + e1;
        #pragma unroll
        for (int off=32; off; off>>=1) ssum += __shfl_xor(ssum, off);
        float inv = __fdividef(1.f, ssum);
        sSIM[lane*HS + p]      = e0*inv;
        sSIM[(lane+64)*HS + p] = e1*inv;
    }
    __syncthreads();

    // ---------------- phase 3: ev -> gsea -> @Wo -> reductions ----------------
    const int dcol = 16*w + l15;
    bf16x8_t bWo[8];
    #pragma unroll
    for (int ks=0; ks<8; ++ks)
        bWo[ks] = *(const bf16x8_t*)(WoT + (size_t)dcol*DI + 32*ks + 8*g4);

    float acc_h = 0.f;
    float a_r1[M1] = {0,0,0}, a_x1[M1] = {0,0,0};
    float a_r2[M2] = {0,0,0,0,0}, a_x2[M2] = {0,0,0,0,0};

    const float* vrow  = v_ws  + (size_t)(b*NN + jcol)*SDI;
    const float* pvrow = pv_ws + (size_t)(b*NN + jcol)*SDI;

    for (int s=0; s<SS; ++s){
        // 3a: ev tile + gsea, write swizzled bf16 s_P rows (this wave's jcol)
        for (int mtl=0; mtl<16; ++mtl){
            const unsigned short* ap = WevT + (size_t)(s*DI + mtl*16 + l15)*DD + 8*g4;
            f32x4_t c = {0.f,0.f,0.f,0.f};
            #pragma unroll
            for (int ks=0; ks<4; ++ks){
                bf16x8_t a = *(const bf16x8_t*)(ap + 32*ks);
                c = __builtin_amdgcn_mfma_f32_16x16x32_bf16(a, bT[ks], c, 0, 0, 0);
            }
            int c0 = mtl*16 + 4*g4;
            float4 vv  = *(const float4*)(vrow  + s*DI + c0);
            float4 pv4 = *(const float4*)(pvrow + s*DI + c0);
            int hh = (mtl>>1) & 7;
            float at = sSIM[jcol*HS + hh*SS + s];
            float gt = sG[hh*SS + s];
            float gg0 = (at*vv.x + c[0]*pv4.x)*gt;
            float gg1 = (at*vv.y + c[1]*pv4.y)*gt;
            float gg2 = (at*vv.z + c[2]*pv4.z)*gt;
            float gg3 = (at*vv.w + c[3]*pv4.w)*gt;
            uint2 pkk; pkk.x = pk2(gg0,gg1); pkk.y = pk2(gg2,gg3);
            int addr = jcol*512 + ((2*c0) ^ ((jcol&7)<<4));
            *(uint2*)(sm + addr) = pkk;
        }
        __syncthreads();
        // 3b: OUT_s = P @ Wo, this wave owns d-tile w
        for (int jt=0; jt<8; ++jt){
            f32x4_t c = {0.f,0.f,0.f,0.f};
            int arow = 16*jt + l15;
            #pragma unroll
            for (int ks=0; ks<8; ++ks){
                int addr = arow*512 + ((2*(32*ks + 8*g4)) ^ ((arow&7)<<4));
                bf16x8_t a = *(const bf16x8_t*)(sm + addr);
                c = __builtin_amdgcn_mfma_f32_16x16x32_bf16(a, bWo[ks], c, 0, 0, 0);
            }
            int j0 = 16*jt + 4*g4;
            if (s == 0){
                acc_h += c[0]+c[1]+c[2]+c[3];
            } else if (s == 1){
                #pragma unroll
                for (int r=0; r<4; ++r){
                    float cv = c[r];
                    #pragma unroll
                    for (int m=0; m<M1; ++m) a_r1[m] = fmaf(sR1[(j0+r)*M1+m], cv, a_r1[m]);
                }
            } else if (s == 2){
                #pragma unroll
                for (int r=0; r<4; ++r){
                    float cv = c[r];
                    #pragma unroll
                    for (int m=0; m<M2; ++m) a_r2[m] = fmaf(sR2[(j0+r)*M2+m], cv, a_r2[m]);
                }
            } else if (s == 3){
                #pragma unroll
                for (int r=0; r<4; ++r){
                    float cv = c[r];
                    const float* xb = x1 + ((size_t)(b*NN + j0 + r)*DD + dcol)*M1;
                    #pragma unroll
                    for (int m=0; m<M1; ++m) a_x1[m] = fmaf(xb[m], cv, a_x1[m]);
                }
            } else {
                #pragma unroll
                for (int r=0; r<4; ++r){
                    float cv = c[r];
                    const float* xb = x2 + ((size_t)(b*NN + j0 + r)*DD + dcol)*M2;
                    #pragma unroll
                    for (int m=0; m<M2; ++m) a_x2[m] = fmaf(xb[m], cv, a_x2[m]);
                }
            }
        }
        __syncthreads();
    }

    acc_h += __shfl_xor(acc_h, 16); acc_h += __shfl_xor(acc_h, 32);
    #pragma unroll
    for (int m=0; m<M1; ++m){
        float t = a_r1[m] + a_x1[m];
        t += __shfl_xor(t, 16); t += __shfl_xor(t, 32);
        a_r1[m] = t;
    }
    #pragma unroll
    for (int m=0; m<M2; ++m){
        float t = a_r2[m] + a_x2[m];
        t += __shfl_xor(t, 16); t += __shfl_xor(t, 32);
        a_r2[m] = t;
    }
    if (g4 == 0){
        out_h[node*DD + dcol] = h[node*DD + dcol] + acc_h;
        #pragma unroll
        for (int m=0; m<M1; ++m) out_x1[(node*DD + dcol)*M1 + m] = a_r1[m];
        #pragma unroll
        for (int m=0; m<M2; ++m) out_x2[(node*DD + dcol)*M2 + m] = a_r2[m];
    }
}

// ---------------------------------------------------------------------------
extern "C" void kernel_launch(void* const* d_in, const int* in_sizes, int n_in,
                              void* d_out, int out_size, void* d_ws, size_t ws_size,
                              hipStream_t stream)
{
    (void)in_sizes; (void)n_in; (void)out_size; (void)ws_size;
    const float* h    = (const float*)d_in[0];
    const float* t_ij = (const float*)d_in[1];
    const float* r1   = (const float*)d_in[2];
    const float* r2   = (const float*)d_in[3];
    const float* x1   = (const float*)d_in[4];
    const float* x2   = (const float*)d_in[5];
    const float* g_hi = (const float*)d_in[6];
    const float* g_hj = (const float*)d_in[7];
    const float* Wq   = (const float*)d_in[8];
    const float* Wk   = (const float*)d_in[9];
    const float* Wv1  = (const float*)d_in[10];
    const float* bv1  = (const float*)d_in[11];
    const float* Wv2  = (const float*)d_in[12];
    const float* bv2  = (const float*)d_in[13];
    const float* Wpv1 = (const float*)d_in[14];
    const float* bpv1 = (const float*)d_in[15];
    const float* Wpv2 = (const float*)d_in[16];
    const float* bpv2 = (const float*)d_in[17];
    const float* Wek  = (const float*)d_in[18];
    const float* Wev  = (const float*)d_in[19];
    const float* Wg   = (const float*)d_in[20];
    const float* bg   = (const float*)d_in[21];
    const float* Wo   = (const float*)d_in[22];

    float* ws    = (float*)d_ws;
    float* q_ws  = ws;                       // 65536
    float* k_ws  = q_ws  + BB*NN*DI;         // 65536
    float* v_ws  = k_ws  + BB*NN*DI;         // 327680
    float* pv_ws = v_ws  + BB*NN*SDI;        // 327680
    float* g_ws  = pv_ws + BB*NN*SDI;        // 10240
    unsigned short* WekT   = (unsigned short*)(g_ws + BB*NN*HS);
    unsigned short* WevT   = WekT + SDI*DD;          // 163840
    unsigned short* WoT    = WevT + SDI*DD;          // 32768
    unsigned short* W2T    = WoT  + DD*DI;           // 1310720
    unsigned short* hid_ws = W2T  + 2*SDI*DM;        // 262144

    float* out_h  = (float*)d_out;
    float* out_x1 = out_h  + BB*NN*DD;
    float* out_x2 = out_x1 + BB*NN*DD*M1;

    (void)hipFuncSetAttribute((const void*)edge_kernel,
        hipFuncAttributeMaxDynamicSharedMemorySize, SM_TOTAL);

    pack_weights<<<512, 256, 0, stream>>>(Wek, Wev, Wo, Wv2, Wpv2,
        WekT, WevT, WoT, W2T);

    node_pre<<<BB*NN, 256, 0, stream>>>(h, g_hi, g_hj, Wq, Wk, Wv1, bv1,
        Wpv1, bpv1, Wg, bg, q_ws, k_ws, hid_ws, g_ws);

    v2_gemm<<<640, 256, 0, stream>>>(hid_ws, W2T, bv2, bpv2, v_ws, pv_ws);

    edge_kernel<<<BB*NN, 512, SM_TOTAL, stream>>>(h, t_ij, r1, r2, x1, x2,
        WekT, WevT, WoT, q_ws, k_ws, v_ws, pv_ws, g_ws, out_h, out_x1, out_x2);
}

// Round 4
// 238.546 us; speedup vs baseline: 6.7411x; 1.1729x over previous
//
#include <hip/hip_runtime.h>
#include <math.h>

#define BB 2
#define NN 128
#define DD 128     // DIM
#define DI 256     // H*DH
#define DM 512
#define SS 5
#define SDI 1280   // S*DI
#define HS 40      // H*S
#define M1 3
#define M2 5

typedef __attribute__((ext_vector_type(8))) short bf16x8_t;
typedef __attribute__((ext_vector_type(4))) float f32x4_t;

#define MFMA __builtin_amdgcn_mfma_f32_16x16x32_bf16

__device__ __forceinline__ float sigm(float x){ return __fdividef(1.0f, 1.0f + __expf(-x)); }
__device__ __forceinline__ unsigned short f2bf(float f){
    union { float f; unsigned u; } v; v.f = f;
    unsigned r = v.u + 0x7FFFu + ((v.u>>16)&1u);   // RNE
    return (unsigned short)(r>>16);
}
__device__ __forceinline__ unsigned pk2(float a, float b){
    return (unsigned)f2bf(a) | ((unsigned)f2bf(b)<<16);
}
__device__ __forceinline__ float bflo(unsigned u){ union{unsigned u; float f;} v; v.u = u<<16; return v.f; }
__device__ __forceinline__ float bfhi(unsigned u){ union{unsigned u; float f;} v; v.u = u & 0xFFFF0000u; return v.f; }

// ---------------------------------------------------------------------------
// prep: tiled f32->bf16 transposes of Wv2/Wpv2/Wek/Wev/Wo; WnT gather; LN.
// grid 664 x 256.
// ---------------------------------------------------------------------------
__global__ __launch_bounds__(256) void prep(
    const float* __restrict__ h,
    const float* __restrict__ g_hi, const float* __restrict__ g_hj,
    const float* __restrict__ Wq, const float* __restrict__ Wk,
    const float* __restrict__ Wv1, const float* __restrict__ Wpv1,
    const float* __restrict__ Wg,
    const float* __restrict__ Wek, const float* __restrict__ Wev,
    const float* __restrict__ Wo, const float* __restrict__ Wv2,
    const float* __restrict__ Wpv2,
    unsigned short* __restrict__ hi_ws, unsigned short* __restrict__ hj_ws,
    unsigned short* __restrict__ WekT, unsigned short* __restrict__ WevT,
    unsigned short* __restrict__ WoT, unsigned short* __restrict__ W2T,
    unsigned short* __restrict__ WnT)
{
    const int bx = blockIdx.x, tid = threadIdx.x;
    __shared__ unsigned short sLT[64*65];
    if (bx < 408){
        const float* src; unsigned short* dst; int W, ldD, R0, C0;
        int t = bx;
        if (t < 160){ src=Wv2;  dst=W2T;            W=SDI; ldD=DM;  R0=(t%20)*64; C0=(t/20)*64; }
        else if (t < 320){ t-=160; src=Wpv2; dst=W2T + SDI*DM; W=SDI; ldD=DM; R0=(t%20)*64; C0=(t/20)*64; }
        else if (t < 360){ t-=320; src=Wek; dst=WekT; W=SDI; ldD=DD; R0=(t%20)*64; C0=(t/20)*64; }
        else if (t < 400){ t-=360; src=Wev; dst=WevT; W=SDI; ldD=DD; R0=(t%20)*64; C0=(t/20)*64; }
        else { t-=400; src=Wo; dst=WoT; W=DD; ldD=DI; R0=(t%2)*64; C0=(t/2)*64; }
        const int tx = tid & 63, ty = tid >> 6;
        #pragma unroll
        for (int k=0;k<16;++k){
            int c = C0 + 4*k + ty;
            sLT[tx*65 + 4*k + ty] = f2bf(src[(size_t)c*W + R0 + tx]);
        }
        __syncthreads();
        #pragma unroll
        for (int k=0;k<16;++k){
            int rr = 4*k + ty;
            dst[(size_t)(R0+rr)*ldD + C0 + tx] = sLT[rr*65 + tx];
        }
    } else {
        const int node = bx - 408;
        if (tid < 64){
            float h0 = h[node*DD + tid], h1 = h[node*DD + 64 + tid];
            float s1 = h0 + h1, s2 = h0*h0 + h1*h1;
            #pragma unroll
            for (int off=32; off; off>>=1){ s1 += __shfl_xor(s1,off); s2 += __shfl_xor(s2,off); }
            float mu   = s1*(1.0f/DD);
            float var  = s2*(1.0f/DD) - mu*mu;
            float rstd = rsqrtf(var + 1e-5f);
            float c0 = (h0-mu)*rstd, c1 = (h1-mu)*rstd;
            hi_ws[node*DD + tid]      = f2bf(c0*g_hi[tid]);
            hi_ws[node*DD + 64 + tid] = f2bf(c1*g_hi[64+tid]);
            hj_ws[node*DD + tid]      = f2bf(c0*g_hj[tid]);
            hj_ws[node*DD + 64 + tid] = f2bf(c1*g_hj[64+tid]);
        }
        // WnT rows: 0..255 Wq | 256..303 Wg(40)+pad | 304..559 Wk | 560..1071 Wv1 | 1072..1583 Wpv1
        for (int f = node*256 + tid; f < 1584*DD; f += 256*256){
            int row = f >> 7, d = f & 127;
            float v;
            if (row < 256)       v = Wq[d*DI + row];
            else if (row < 304){ int c = row-256; v = (c < HS) ? Wg[d*HS + c] : 0.0f; }
            else if (row < 560)  v = Wk[d*DI + (row-304)];
            else if (row < 1072) v = Wv1[d*DM + (row-560)];
            else                 v = Wpv1[d*DM + (row-1072)];
            WnT[f] = f2bf(v);
        }
    }
}

// ---------------------------------------------------------------------------
// node_gemm: [cols 1584] x [256 nodes] = WnT @ (hi|hj)^T via MFMA.
// grid 396 = 99 col-tiles x 4 node-quarters; 256 thr = 4 waves.
// ---------------------------------------------------------------------------
__global__ __launch_bounds__(256,4) void node_gemm(
    const unsigned short* __restrict__ WnT,
    const unsigned short* __restrict__ hi_ws, const unsigned short* __restrict__ hj_ws,
    const float* __restrict__ bg, const float* __restrict__ bv1, const float* __restrict__ bpv1,
    float* __restrict__ q_ws, float* __restrict__ k_ws,
    float* __restrict__ g_ws, unsigned short* __restrict__ hid_ws)
{
    const int bx = blockIdx.x;
    const int tile = bx % 99, nq = bx / 99;
    const int tid = threadIdx.x, lane = tid&63, w = tid>>6;
    const int l15 = lane&15, g4 = lane>>4;
    const int ntile = nq*4 + w;
    const unsigned short* A  = WnT + (size_t)(tile*16 + l15)*DD + 8*g4;
    const unsigned short* Bp = ((tile < 19) ? hi_ws : hj_ws) + (size_t)(ntile*16 + l15)*DD + 8*g4;
    f32x4_t c = {0.f,0.f,0.f,0.f};
    #pragma unroll
    for (int ks=0; ks<4; ++ks)
        c = MFMA(*(const bf16x8_t*)(A + 32*ks), *(const bf16x8_t*)(Bp + 32*ks), c, 0,0,0);
    const int node = ntile*16 + l15;
    const int col0 = tile*16 + 4*g4;
    if (tile < 16){
        f32x4_t* dst = (f32x4_t*)(q_ws + (size_t)node*DI + col0);
        *dst = c;
    } else if (tile < 19){
        #pragma unroll
        for (int r=0;r<4;++r){
            int cc = col0 + r - 256;
            if (cc < HS) g_ws[node*HS + cc] = sigm(c[r] + bg[cc]);
        }
    } else if (tile < 35){
        f32x4_t* dst = (f32x4_t*)(k_ws + (size_t)node*DI + (col0-304));
        *dst = c;
    } else if (tile < 67){
        int cc = col0 - 560;
        float s0 = c[0]+bv1[cc], s1 = c[1]+bv1[cc+1], s2 = c[2]+bv1[cc+2], s3 = c[3]+bv1[cc+3];
        s0 *= sigm(s0); s1 *= sigm(s1); s2 *= sigm(s2); s3 *= sigm(s3);
        uint2 pkk; pkk.x = pk2(s0,s1); pkk.y = pk2(s2,s3);
        *(uint2*)(hid_ws + (size_t)node*1024 + cc) = pkk;
    } else {
        int cc = col0 - 1072;
        float s0 = c[0]+bpv1[cc], s1 = c[1]+bpv1[cc+1], s2 = c[2]+bpv1[cc+2], s3 = c[3]+bpv1[cc+3];
        s0 *= sigm(s0); s1 *= sigm(s1); s2 *= sigm(s2); s3 *= sigm(s3);
        uint2 pkk; pkk.x = pk2(s0,s1); pkk.y = pk2(s2,s3);
        *(uint2*)(hid_ws + (size_t)node*1024 + 512 + cc) = pkk;
    }
}

// ---------------------------------------------------------------------------
// v2_gemm: vpv[node][2560] = W2T @ hid^T (+bias), bf16 out.
// grid 640 = 160 o-tiles x 4 node-quarters.
// ---------------------------------------------------------------------------
__global__ __launch_bounds__(256,4) void v2_gemm(
    const unsigned short* __restrict__ W2T,
    const unsigned short* __restrict__ hid_ws,
    const float* __restrict__ bv2, const float* __restrict__ bpv2,
    unsigned short* __restrict__ vpv_ws)
{
    const int bx = blockIdx.x;
    const int otile = bx % 160, nq = bx / 160;
    const int tid = threadIdx.x, lane = tid&63, w = tid>>6;
    const int l15 = lane&15, g4 = lane>>4;
    const int ntile = nq*4 + w;
    const int obase = otile*16;
    const int koff = (obase < SDI) ? 0 : 512;
    const unsigned short* A  = W2T + (size_t)(obase + l15)*DM + 8*g4;
    const unsigned short* Bp = hid_ws + (size_t)(ntile*16 + l15)*1024 + koff + 8*g4;
    f32x4_t c = {0.f,0.f,0.f,0.f};
    #pragma unroll
    for (int ks=0; ks<16; ++ks)
        c = MFMA(*(const bf16x8_t*)(A + 32*ks), *(const bf16x8_t*)(Bp + 32*ks), c, 0,0,0);
    const int node = ntile*16 + l15;
    const int o0 = obase + 4*g4;
    const float* bias = (obase < SDI) ? bv2 : bpv2;
    const int ob = (obase < SDI) ? o0 : (o0 - SDI);
    float v0 = c[0]+bias[ob], v1 = c[1]+bias[ob+1], v2 = c[2]+bias[ob+2], v3 = c[3]+bias[ob+3];
    uint2 pkk; pkk.x = pk2(v0,v1); pkk.y = pk2(v2,v3);
    *(uint2*)(vpv_ws + (size_t)node*2560 + o0) = pkk;
}

// ---------------------------------------------------------------------------
// sim_kernel: sim[j,h,s] = sum_dh QK[j,dh]*silu(ek[j,dh]) per (node, j-half).
// grid 512 = 256 nodes x 2 halves; 256 thr = 4 waves.
// LDS: sQK @0 (32KB), sT @32768 (16KB, overlaid by sSIM), sQf @49152.
// ---------------------------------------------------------------------------
__global__ __launch_bounds__(256,2) void sim_kernel(
    const float* __restrict__ t_ij,
    const unsigned short* __restrict__ WekT,
    const float* __restrict__ q_ws, const float* __restrict__ k_ws,
    float* __restrict__ sim_ws)
{
    __shared__ __align__(16) char sm[50176];
    float* sSIM = (float*)(sm + 32768);
    float* sQf  = (float*)(sm + 49152);

    const int bx = blockIdx.x;
    const int node = bx >> 1, jh = bx & 1;
    const int b = node >> 7;
    const int j0 = jh*64;
    const int tid = threadIdx.x, lane = tid&63, w = tid>>6;
    const int l15 = lane&15, g4 = lane>>4;

    sQf[tid] = q_ws[(size_t)node*DI + tid];
    {   // stage T -> bf16 swizzled @32768
        const int j = tid>>2, seg = tid&3;
        const float* src = t_ij + (size_t)(node*NN + j0 + j)*DD + seg*32;
        char* row = sm + 32768 + j*256;
        const int swz = (j&7)<<4;
        #pragma unroll
        for (int u=0;u<8;++u){
            float4 tv = *(const float4*)(src + 4*u);
            uint2 pkk; pkk.x = pk2(tv.x,tv.y); pkk.y = pk2(tv.z,tv.w);
            *(uint2*)(row + ((2*(seg*32+4*u)) ^ swz)) = pkk;
        }
    }
    __syncthreads();
    {   // QK build -> bf16 swizzled @0
        const int j = tid>>2, seg = tid&3;
        const float* kr = k_ws + (size_t)(b*NN + j0 + j)*DI + seg*64;
        char* row = sm + j*512;
        const int swz = (j&7)<<4;
        #pragma unroll
        for (int u=0;u<16;++u){
            float4 kv = *(const float4*)(kr + 4*u);
            const float* qv = sQf + seg*64 + 4*u;
            uint2 pkk; pkk.x = pk2(kv.x*qv[0], kv.y*qv[1]); pkk.y = pk2(kv.z*qv[2], kv.w*qv[3]);
            *(uint2*)(row + ((2*(seg*64+4*u)) ^ swz)) = pkk;
        }
    }
    bf16x8_t bT[4][4];
    #pragma unroll
    for (int js=0; js<4; ++js){
        const int jc = js*16 + l15;
        const char* row = sm + 32768 + jc*256;
        const int swz = (jc&7)<<4;
        #pragma unroll
        for (int ks=0; ks<4; ++ks)
            bT[js][ks] = *(const bf16x8_t*)(row + ((2*(32*ks + 8*g4)) ^ swz));
    }
    __syncthreads();   // QK ready; bT reads done before sSIM overlays sT

    const unsigned short* Wbase = WekT + (size_t)l15*DD + 8*g4;
    bf16x8_t a0[4], a1[4];
    {
        const unsigned short* ap = Wbase + (size_t)(2*w)*16*DD;
        #pragma unroll
        for (int ks=0;ks<4;++ks){
            a0[ks] = *(const bf16x8_t*)(ap + 32*ks);
            a1[ks] = *(const bf16x8_t*)(ap + 2048 + 32*ks);
        }
    }
    for (int p8=0; p8<10; ++p8){
        const int p = 4*p8 + w;
        bf16x8_t na0[4], na1[4];
        if (p8 < 9){
            const unsigned short* ap = Wbase + (size_t)(2*(p+4))*16*DD;
            #pragma unroll
            for (int ks=0;ks<4;++ks){
                na0[ks] = *(const bf16x8_t*)(ap + 32*ks);
                na1[ks] = *(const bf16x8_t*)(ap + 2048 + 32*ks);
            }
        }
        const int hs = (p&7)*SS + (p>>3);
        const int o0 = 32*p + 4*g4;
        const int qk0 = o0 & 255;              // ek col -> QK elem (mod DI)
        #pragma unroll
        for (int js=0; js<4; ++js){
            f32x4_t c0 = {0.f,0.f,0.f,0.f}, c1 = {0.f,0.f,0.f,0.f};
            #pragma unroll
            for (int ks=0; ks<4; ++ks){
                c0 = MFMA(a0[ks], bT[js][ks], c0, 0,0,0);
                c1 = MFMA(a1[ks], bT[js][ks], c1, 0,0,0);
            }
            const int jr = js*16 + l15;
            const char* qrow = sm + jr*512;
            const int swz = (jr&7)<<4;
            uint2 u0 = *(const uint2*)(qrow + ((2*qk0) ^ swz));
            uint2 u1 = *(const uint2*)(qrow + ((2*(qk0+16)) ^ swz));
            float part =
                (c0[0]*sigm(c0[0]))*bflo(u0.x) + (c0[1]*sigm(c0[1]))*bfhi(u0.x)
              + (c0[2]*sigm(c0[2]))*bflo(u0.y) + (c0[3]*sigm(c0[3]))*bfhi(u0.y)
              + (c1[0]*sigm(c1[0]))*bflo(u1.x) + (c1[1]*sigm(c1[1]))*bfhi(u1.x)
              + (c1[2]*sigm(c1[2]))*bflo(u1.y) + (c1[3]*sigm(c1[3]))*bfhi(u1.y);
            part += __shfl_xor(part, 16);
            part += __shfl_xor(part, 32);
            if (g4 == 0) sSIM[jr*HS + hs] = part;
        }
        if (p8 < 9){
            #pragma unroll
            for (int ks=0;ks<4;++ks){ a0[ks]=na0[ks]; a1[ks]=na1[ks]; }
        }
    }
    __syncthreads();
    {
        float* dst = sim_ws + (size_t)node*NN*HS + j0*HS;
        for (int t2=tid; t2<64*HS; t2+=256) dst[t2] = sSIM[t2];
    }
}

// ---------------------------------------------------------------------------
// out_kernel: softmax (from sim_ws) -> ev -> gsea -> @Wo -> j-reduced partials.
// grid 512 = 256 nodes x 2 halves; 256 thr = 4 waves.
// LDS: sP @0 (32KB, sT in first 16KB during prologue), sAT @32768, rest after.
// ---------------------------------------------------------------------------
__global__ __launch_bounds__(256,2) void out_kernel(
    const float* __restrict__ t_ij,
    const unsigned short* __restrict__ WevT, const unsigned short* __restrict__ WoT,
    const unsigned short* __restrict__ vpv_ws,
    const float* __restrict__ g_ws, const float* __restrict__ sim_ws,
    const float* __restrict__ r1, const float* __restrict__ r2,
    const float* __restrict__ x1, const float* __restrict__ x2,
    float* __restrict__ p_ws)
{
    __shared__ __align__(16) char sm[45216];
    float* sAT = (float*)(sm + 32768);   // 64*40 f32
    float* sG  = (float*)(sm + 43008);   // 40
    float* sR1 = (float*)(sm + 43168);   // 192
    float* sR2 = (float*)(sm + 43936);   // 320

    const int bx = blockIdx.x;
    const int node = bx >> 1, jh = bx & 1;
    const int b = node >> 7;
    const int j0 = jh*64;
    const int tid = threadIdx.x, lane = tid&63, w = tid>>6;
    const int l15 = lane&15, g4 = lane>>4;

    {   // stage T @0
        const int j = tid>>2, seg = tid&3;
        const float* src = t_ij + (size_t)(node*NN + j0 + j)*DD + seg*32;
        char* row = sm + j*256;
        const int swz = (j&7)<<4;
        #pragma unroll
        for (int u=0;u<8;++u){
            float4 tv = *(const float4*)(src + 4*u);
            uint2 pkk; pkk.x = pk2(tv.x,tv.y); pkk.y = pk2(tv.z,tv.w);
            *(uint2*)(row + ((2*(seg*32+4*u)) ^ swz)) = pkk;
        }
    }
    if (tid < HS) sG[tid] = g_ws[node*HS + tid];
    if (tid < 192) sR1[tid] = r1[((size_t)node*NN + j0)*M1 + tid];
    for (int t2=tid; t2<320; t2+=256) sR2[t2] = r2[((size_t)node*NN + j0)*M2 + t2];
    {   // softmax over full j; keep our half's attn
        const float* srow = sim_ws + (size_t)node*NN*HS;
        #pragma unroll
        for (int u=0; u<10; ++u){
            const int hs = w*10 + u;
            float v0 = srow[lane*HS + hs];
            float v1 = srow[(lane+64)*HS + hs];
            float m = fmaxf(v0,v1);
            #pragma unroll
            for (int off=32; off; off>>=1) m = fmaxf(m, __shfl_xor(m,off));
            float e0 = __expf(v0-m), e1 = __expf(v1-m);
            float ssum = e0+e1;
            #pragma unroll
            for (int off=32; off; off>>=1) ssum += __shfl_xor(ssum,off);
            sAT[lane*HS + hs] = ((jh==0) ? e0 : e1) * __fdividef(1.0f, ssum);
        }
    }
    __syncthreads();
    bf16x8_t bTw[4];
    {
        const int jc = 16*w + l15;
        const char* row = sm + jc*256;
        const int swz = (jc&7)<<4;
        #pragma unroll
        for (int ks=0;ks<4;++ks) bTw[ks] = *(const bf16x8_t*)(row + ((2*(32*ks+8*g4)) ^ swz));
    }
    bf16x8_t bWo[2][8];
    #pragma unroll
    for (int slot=0; slot<2; ++slot){
        const unsigned short* wr = WoT + (size_t)((w+4*slot)*16 + l15)*DI + 8*g4;
        #pragma unroll
        for (int ks=0;ks<8;++ks) bWo[slot][ks] = *(const bf16x8_t*)(wr + 32*ks);
    }
    __syncthreads();   // all bTw reads done before sP overwrites sT

    const int jrow  = 16*w + l15;
    const int jglob = j0 + jrow;
    const unsigned short* vbase = vpv_ws + (size_t)(b*NN + jglob)*2560;
    char* prow = sm + jrow*512;
    const int pswz = (jrow&7)<<4;

    float ah[2] = {0.f,0.f};
    float ax1[2][M1] = {{0.f,0.f,0.f},{0.f,0.f,0.f}};
    float ax2[2][M2] = {{0.f,0.f,0.f,0.f,0.f},{0.f,0.f,0.f,0.f,0.f}};

    for (int s=0; s<SS; ++s){
        // 3a: ev tile (this wave's 16 j-rows), gsea -> sP
        const unsigned short* ap0 = WevT + (size_t)(s*DI + l15)*DD + 8*g4;
        bf16x8_t aa[4];
        #pragma unroll
        for (int ks=0;ks<4;++ks) aa[ks] = *(const bf16x8_t*)(ap0 + 32*ks);
        for (int mtl=0; mtl<16; ++mtl){
            bf16x8_t na[4];
            if (mtl < 15){
                const unsigned short* ap = ap0 + (size_t)(mtl+1)*16*DD;
                #pragma unroll
                for (int ks=0;ks<4;++ks) na[ks] = *(const bf16x8_t*)(ap + 32*ks);
            }
            f32x4_t c = {0.f,0.f,0.f,0.f};
            #pragma unroll
            for (int ks=0;ks<4;++ks) c = MFMA(aa[ks], bTw[ks], c, 0,0,0);
            const int o4 = mtl*16 + 4*g4;
            const int hh = o4 >> 5;
            uint2 vvp = *(const uint2*)(vbase + s*DI + o4);
            uint2 pvp = *(const uint2*)(vbase + SDI + s*DI + o4);
            const float at = sAT[jrow*HS + hh*SS + s];
            const float gt = sG[hh*SS + s];
            float q0 = (at*bflo(vvp.x) + c[0]*bflo(pvp.x))*gt;
            float q1 = (at*bfhi(vvp.x) + c[1]*bfhi(pvp.x))*gt;
            float q2 = (at*bflo(vvp.y) + c[2]*bflo(pvp.y))*gt;
            float q3 = (at*bfhi(vvp.y) + c[3]*bfhi(pvp.y))*gt;
            uint2 pkk; pkk.x = pk2(q0,q1); pkk.y = pk2(q2,q3);
            *(uint2*)(prow + ((2*o4) ^ pswz)) = pkk;
            if (mtl < 15){
                #pragma unroll
                for (int ks=0;ks<4;++ks) aa[ks]=na[ks];
            }
        }
        __syncthreads();
        // 3b: OUT_s = P @ Wo; accumulate reductions
        #pragma unroll
        for (int slot=0; slot<2; ++slot){
            #pragma unroll
            for (int jsub=0; jsub<4; ++jsub){
                const int arow = jsub*16 + l15;
                const char* pb = sm + arow*512;
                const int aswz = (arow&7)<<4;
                f32x4_t c = {0.f,0.f,0.f,0.f};
                #pragma unroll
                for (int ks=0;ks<8;++ks){
                    bf16x8_t a = *(const bf16x8_t*)(pb + ((64*ks + 16*g4) ^ aswz));
                    c = MFMA(a, bWo[slot][ks], c, 0,0,0);
                }
                const int jl = jsub*16 + 4*g4;
                const int d  = (w + 4*slot)*16 + l15;
                if (s == 0){
                    ah[slot] += c[0]+c[1]+c[2]+c[3];
                } else if (s == 1){
                    #pragma unroll
                    for (int r=0;r<4;++r){
                        #pragma unroll
                        for (int m=0;m<M1;++m) ax1[slot][m] = fmaf(sR1[(jl+r)*M1+m], c[r], ax1[slot][m]);
                    }
                } else if (s == 2){
                    #pragma unroll
                    for (int r=0;r<4;++r){
                        #pragma unroll
                        for (int m=0;m<M2;++m) ax2[slot][m] = fmaf(sR2[(jl+r)*M2+m], c[r], ax2[slot][m]);
                    }
                } else if (s == 3){
                    #pragma unroll
                    for (int r=0;r<4;++r){
                        const float* xb = x1 + ((size_t)(b*NN + j0 + jl + r)*DD + d)*M1;
                        #pragma unroll
                        for (int m=0;m<M1;++m) ax1[slot][m] = fmaf(xb[m], c[r], ax1[slot][m]);
                    }
                } else {
                    #pragma unroll
                    for (int r=0;r<4;++r){
                        const float* xb = x2 + ((size_t)(b*NN + j0 + jl + r)*DD + d)*M2;
                        #pragma unroll
                        for (int m=0;m<M2;++m) ax2[slot][m] = fmaf(xb[m], c[r], ax2[slot][m]);
                    }
                }
            }
        }
        __syncthreads();
    }
    // reduce across g4 groups, write partials
    #pragma unroll
    for (int slot=0; slot<2; ++slot){
        const int d = (w+4*slot)*16 + l15;
        float v0 = ah[slot];
        float v1 = ax1[slot][0], v2 = ax1[slot][1], v3 = ax1[slot][2];
        float v4 = ax2[slot][0], v5 = ax2[slot][1], v6 = ax2[slot][2], v7 = ax2[slot][3], v8 = ax2[slot][4];
        v0 += __shfl_xor(v0,16); v0 += __shfl_xor(v0,32);
        v1 += __shfl_xor(v1,16); v1 += __shfl_xor(v1,32);
        v2 += __shfl_xor(v2,16); v2 += __shfl_xor(v2,32);
        v3 += __shfl_xor(v3,16); v3 += __shfl_xor(v3,32);
        v4 += __shfl_xor(v4,16); v4 += __shfl_xor(v4,32);
        v5 += __shfl_xor(v5,16); v5 += __shfl_xor(v5,32);
        v6 += __shfl_xor(v6,16); v6 += __shfl_xor(v6,32);
        v7 += __shfl_xor(v7,16); v7 += __shfl_xor(v7,32);
        v8 += __shfl_xor(v8,16); v8 += __shfl_xor(v8,32);
        if (g4 == 0){
            float* pb = p_ws + ((size_t)(jh*256 + node)*9)*DD + d;
            pb[0*DD] = v0;
            pb[1*DD] = v1; pb[2*DD] = v2; pb[3*DD] = v3;
            pb[4*DD] = v4; pb[5*DD] = v5; pb[6*DD] = v6; pb[7*DD] = v7; pb[8*DD] = v8;
        }
    }
}

// ---------------------------------------------------------------------------
// combine: sum the two j-half partials, add residual, write outputs.
// ---------------------------------------------------------------------------
__global__ __launch_bounds__(128) void combine(
    const float* __restrict__ h, const float* __restrict__ p_ws,
    float* __restrict__ out_h, float* __restrict__ out_x1, float* __restrict__ out_x2)
{
    const int node = blockIdx.x, d = threadIdx.x;
    const float* p0 = p_ws + ((size_t)node*9)*DD + d;
    const float* p1 = p_ws + ((size_t)(256 + node)*9)*DD + d;
    out_h[(size_t)node*DD + d] = h[(size_t)node*DD + d] + p0[0] + p1[0];
    #pragma unroll
    for (int m=0;m<M1;++m) out_x1[((size_t)node*DD + d)*M1 + m] = p0[(1+m)*DD] + p1[(1+m)*DD];
    #pragma unroll
    for (int m=0;m<M2;++m) out_x2[((size_t)node*DD + d)*M2 + m] = p0[(4+m)*DD] + p1[(4+m)*DD];
}

// ---------------------------------------------------------------------------
extern "C" void kernel_launch(void* const* d_in, const int* in_sizes, int n_in,
                              void* d_out, int out_size, void* d_ws, size_t ws_size,
                              hipStream_t stream)
{
    (void)in_sizes; (void)n_in; (void)out_size; (void)ws_size;
    const float* h    = (const float*)d_in[0];
    const float* t_ij = (const float*)d_in[1];
    const float* r1   = (const float*)d_in[2];
    const float* r2   = (const float*)d_in[3];
    const float* x1   = (const float*)d_in[4];
    const float* x2   = (const float*)d_in[5];
    const float* g_hi = (const float*)d_in[6];
    const float* g_hj = (const float*)d_in[7];
    const float* Wq   = (const float*)d_in[8];
    const float* Wk   = (const float*)d_in[9];
    const float* Wv1  = (const float*)d_in[10];
    const float* bv1  = (const float*)d_in[11];
    const float* Wv2  = (const float*)d_in[12];
    const float* bv2  = (const float*)d_in[13];
    const float* Wpv1 = (const float*)d_in[14];
    const float* bpv1 = (const float*)d_in[15];
    const float* Wpv2 = (const float*)d_in[16];
    const float* bpv2 = (const float*)d_in[17];
    const float* Wek  = (const float*)d_in[18];
    const float* Wev  = (const float*)d_in[19];
    const float* Wg   = (const float*)d_in[20];
    const float* bg   = (const float*)d_in[21];
    const float* Wo   = (const float*)d_in[22];

    float* fb     = (float*)d_ws;
    float* q_ws   = fb;                       // 65536
    float* k_ws   = q_ws   + 65536;           // 65536
    float* g_ws   = k_ws   + 65536;           // 10240
    float* sim_ws = g_ws   + 10240;           // 1310720
    float* p_ws   = sim_ws + 1310720;         // 589824
    unsigned short* hi_ws  = (unsigned short*)(p_ws + 589824);
    unsigned short* hj_ws  = hi_ws  + 32768;
    unsigned short* hid_ws = hj_ws  + 32768;  // 262144
    unsigned short* vpv_ws = hid_ws + 262144; // 655360
    unsigned short* WekT   = vpv_ws + 655360; // 163840
    unsigned short* WevT   = WekT   + 163840; // 163840
    unsigned short* WoT    = WevT   + 163840; // 32768
    unsigned short* W2T    = WoT    + 32768;  // 1310720
    unsigned short* WnT    = W2T    + 1310720;// 202752

    float* out_h  = (float*)d_out;
    float* out_x1 = out_h  + BB*NN*DD;
    float* out_x2 = out_x1 + BB*NN*DD*M1;

    prep<<<664, 256, 0, stream>>>(h, g_hi, g_hj, Wq, Wk, Wv1, Wpv1, Wg,
        Wek, Wev, Wo, Wv2, Wpv2, hi_ws, hj_ws, WekT, WevT, WoT, W2T, WnT);

    node_gemm<<<396, 256, 0, stream>>>(WnT, hi_ws, hj_ws, bg, bv1, bpv1,
        q_ws, k_ws, g_ws, hid_ws);

    v2_gemm<<<640, 256, 0, stream>>>(W2T, hid_ws, bv2, bpv2, vpv_ws);

    sim_kernel<<<512, 256, 0, stream>>>(t_ij, WekT, q_ws, k_ws, sim_ws);

    out_kernel<<<512, 256, 0, stream>>>(t_ij, WevT, WoT, vpv_ws, g_ws, sim_ws,
        r1, r2, x1, x2, p_ws);

    combine<<<256, 128, 0, stream>>>(h, p_ws, out_h, out_x1, out_x2);
}